// Round 2
// baseline (1807.145 us; speedup 1.0000x reference)
//
#include <hip/hip_runtime.h>
#include <hip/hip_bf16.h>

#define BB 256
#define HH 256
#define SSL 512
#define G3 768

using short8 = __attribute__((ext_vector_type(8))) short;
using f32x4  = __attribute__((ext_vector_type(4))) float;

__device__ __forceinline__ unsigned short f2bf(float f) {
  unsigned int u = __float_as_uint(f);
  u += 0x7FFFu + ((u >> 16) & 1u);
  return (unsigned short)(u >> 16);
}
__device__ __forceinline__ float bf2f(unsigned short b) {
  return __uint_as_float(((unsigned int)b) << 16);
}
// barrier that does NOT drain vmcnt (keeps global prefetch in flight);
// lgkmcnt(0) orders all LDS traffic across the barrier.
__device__ __forceinline__ void block_sync_lds() {
  asm volatile("s_waitcnt lgkmcnt(0)\n\ts_barrier" ::: "memory");
}

// ---------------------------------------------------------------------------
// Kernel 1: GI[b][s][j] = sum_h X[b][h][s] * Wih[j][h] + bih[j]   (bf16 out)
// grid (6, 1024): x = j-block so the 6 blocks sharing an X-tile are
// dispatch-adjacent (L2/L3 reuse of X). K-loop software-pipelined: kt+1
// global loads issued before MFMA on kt.
// ---------------------------------------------------------------------------
__global__ __launch_bounds__(512, 4) void gi_gemm(
    const float* __restrict__ X, const float* __restrict__ Wih,
    const float* __restrict__ bih, unsigned short* __restrict__ gi)
{
  __shared__ __align__(16) char smem[36864];
  unsigned short (*Al)[72] = (unsigned short(*)[72])smem;           // 128 x 72 bf16
  unsigned short (*Bl)[72] = (unsigned short(*)[72])(smem + 18432); // 128 x 72 bf16
  float (*Dl)[132] = (float(*)[132])smem;                           // 64 x 132 f32 (epilogue)

  const int tid  = threadIdx.x;
  const int lane = tid & 63;
  const int wave = tid >> 6;
  const int wm   = wave >> 2;   // 0..1  (m 64-half)
  const int wj   = wave & 3;    // 0..3  (j 32-slice)
  const int n16  = lane & 15;
  const int quad = lane >> 4;

  const int mblk = blockIdx.y;          // 0..1023
  const int b    = mblk >> 2;
  const int s0   = (mblk & 3) * 128;
  const int j0   = blockIdx.x * 128;

  f32x4 acc[4][2];
#pragma unroll
  for (int mt = 0; mt < 4; mt++)
#pragma unroll
    for (int jt = 0; jt < 2; jt++) acc[mt][jt] = f32x4{0.f, 0.f, 0.f, 0.f};

  const float* Xb = X + (size_t)b * (HH * SSL);

  float4 va[4], vb[4];
  // prologue: loads for kt = 0
#pragma unroll
  for (int i = 0; i < 4; i++) {
    int hl = (tid >> 5) + 16 * i;
    va[i] = *(const float4*)(Xb + (size_t)(0 * 64 + hl) * SSL + s0 + 4 * (tid & 31));
    int j  = (tid >> 4) + 32 * i;
    vb[i] = *(const float4*)(Wih + (size_t)(j0 + j) * HH + 0 * 64 + 4 * (tid & 15));
  }

  for (int kt = 0; kt < 4; kt++) {
    // stage from regs: A transpose [m=s][k=h], B [j][k] (k contiguous)
#pragma unroll
    for (int i = 0; i < 4; i++) {
      int hl = (tid >> 5) + 16 * i;
      int s4 = tid & 31;
      const float4 v = va[i];
      Al[4 * s4 + 0][hl] = f2bf(v.x);
      Al[4 * s4 + 1][hl] = f2bf(v.y);
      Al[4 * s4 + 2][hl] = f2bf(v.z);
      Al[4 * s4 + 3][hl] = f2bf(v.w);
    }
#pragma unroll
    for (int i = 0; i < 4; i++) {
      int j  = (tid >> 4) + 32 * i;
      int k4 = tid & 15;
      const float4 v = vb[i];
      unsigned long long pk = (unsigned long long)f2bf(v.x)
          | ((unsigned long long)f2bf(v.y) << 16)
          | ((unsigned long long)f2bf(v.z) << 32)
          | ((unsigned long long)f2bf(v.w) << 48);
      *(unsigned long long*)&Bl[j][4 * k4] = pk;
    }
    __syncthreads();
    // prefetch kt+1 while MFMA runs on kt
    if (kt < 3) {
#pragma unroll
      for (int i = 0; i < 4; i++) {
        int hl = (tid >> 5) + 16 * i;
        va[i] = *(const float4*)(Xb + (size_t)((kt + 1) * 64 + hl) * SSL + s0 + 4 * (tid & 31));
        int j  = (tid >> 4) + 32 * i;
        vb[i] = *(const float4*)(Wih + (size_t)(j0 + j) * HH + (kt + 1) * 64 + 4 * (tid & 15));
      }
    }
#pragma unroll
    for (int kk = 0; kk < 2; kk++) {
      short8 af[4], bfr[2];
#pragma unroll
      for (int mt = 0; mt < 4; mt++)
        af[mt] = *(const short8*)&Al[wm * 64 + mt * 16 + n16][kk * 32 + quad * 8];
#pragma unroll
      for (int jt = 0; jt < 2; jt++)
        bfr[jt] = *(const short8*)&Bl[wj * 32 + jt * 16 + n16][kk * 32 + quad * 8];
#pragma unroll
      for (int mt = 0; mt < 4; mt++)
#pragma unroll
        for (int jt = 0; jt < 2; jt++)
          acc[mt][jt] = __builtin_amdgcn_mfma_f32_16x16x32_bf16(af[mt], bfr[jt], acc[mt][jt], 0, 0, 0);
    }
    __syncthreads();
  }

  float bias[2];
  bias[0] = bih[j0 + wj * 32 + 0 * 16 + n16];
  bias[1] = bih[j0 + wj * 32 + 1 * 16 + n16];

  // epilogue via LDS transpose, 2 chunks of 64 rows
  for (int c = 0; c < 2; c++) {
    __syncthreads();
    if (wm == c) {
#pragma unroll
      for (int mt = 0; mt < 4; mt++)
#pragma unroll
        for (int jt = 0; jt < 2; jt++)
#pragma unroll
          for (int r = 0; r < 4; r++)
            Dl[mt * 16 + quad * 4 + r][wj * 32 + jt * 16 + n16] = acc[mt][jt][r] + bias[jt];
    }
    __syncthreads();
#pragma unroll
    for (int i = 0; i < 2; i++) {
      int ml = (tid >> 4) + 32 * i;       // 0..63
      int jj = (tid & 15) * 8;
      float4 p0 = *(const float4*)&Dl[ml][jj];
      float4 p1 = *(const float4*)&Dl[ml][jj + 4];
      short8 st;
      st[0] = (short)f2bf(p0.x); st[1] = (short)f2bf(p0.y);
      st[2] = (short)f2bf(p0.z); st[3] = (short)f2bf(p0.w);
      st[4] = (short)f2bf(p1.x); st[5] = (short)f2bf(p1.y);
      st[6] = (short)f2bf(p1.z); st[7] = (short)f2bf(p1.w);
      int sgl = s0 + c * 64 + ml;
      *(short8*)(gi + ((size_t)b * SSL + sgl) * G3 + j0 + jj) = st;
    }
  }
}

// ---------------------------------------------------------------------------
// Kernel 2: persistent GRU scan. 64 blocks x 4 batch rows, 1024 threads
// (16 waves; wave w owns j-rows [w*16, w*16+16) for all 3 gates).
// W_hh: 24 short8 = 96 VGPR/lane, PINNED via asm so the compiler cannot
// rematerialize the loads inside the loop (R1's 3000 cy/step bug).
// h: bf16 in MFMA-B-fragment layout, double-buffered (2 KB/buf); only
// batch cols 0..3 stored — cols 4..15 of the MFMA read the same data
// (broadcast); their D columns are garbage and never consumed.
// ---------------------------------------------------------------------------
__global__ __launch_bounds__(1024, 4) void gru_scan(
    const float* __restrict__ tree, const int* __restrict__ mask,
    const float* __restrict__ Whh, const float* __restrict__ bhh,
    const unsigned short* __restrict__ gi, float* __restrict__ out)
{
  __shared__ unsigned short hfrag[2][8][4][4][8]; // [buf][kt][b][quad][8 bf16]
  __shared__ float pre[3][4][260];                // gh pre-activations
  __shared__ int lsum[4];

  const int tid  = threadIdx.x;
  const int lane = tid & 63;
  const int w    = tid >> 6;     // wave 0..15
  const int n16  = lane & 15;
  const int quad = lane >> 4;
  const int brow0 = blockIdx.x * 4;

  const int bb = tid >> 8;       // 0..3 (wave-uniform: w>>2)
  const int jp = tid & 255;      // 0..255 element index (j)

  if (tid < 4) lsum[tid] = 0;
  __syncthreads();
  {
    const int* mp = mask + (size_t)(brow0 + bb) * SSL + jp * 2;
    atomicAdd(&lsum[bb], mp[0] + mp[1]);
  }

  // W_hh fragments: wave w, gate g, kt: row = g*256 + w*16 + n16
  short8 aw[3][8];
#pragma unroll
  for (int g = 0; g < 3; g++)
#pragma unroll
    for (int kt = 0; kt < 8; kt++) {
      int row = g * HH + w * 16 + n16;
      int k0  = kt * 32 + quad * 8;
      const float4 v0 = *(const float4*)(Whh + (size_t)row * HH + k0);
      const float4 v1 = *(const float4*)(Whh + (size_t)row * HH + k0 + 4);
      short8 wv;
      wv[0] = (short)f2bf(v0.x); wv[1] = (short)f2bf(v0.y);
      wv[2] = (short)f2bf(v0.z); wv[3] = (short)f2bf(v0.w);
      wv[4] = (short)f2bf(v1.x); wv[5] = (short)f2bf(v1.y);
      wv[6] = (short)f2bf(v1.z); wv[7] = (short)f2bf(v1.w);
      aw[g][kt] = wv;
    }
  // pin: asm "writes" aw -> loads cannot be sunk into the loop
#pragma unroll
  for (int g = 0; g < 3; g++)
#pragma unroll
    for (int kt = 0; kt < 8; kt++)
      asm volatile("" : "+v"(aw[g][kt]));

  float bhr = bhh[0 * HH + jp];
  float bhz = bhh[1 * HH + jp];
  float bhn = bhh[2 * HH + jp];

  // init h: buffer 0
  float h_old = tree[(size_t)(brow0 + bb) * HH + jp];
  hfrag[0][jp >> 5][bb][(jp >> 3) & 3][jp & 7] = f2bf(h_old);
  __syncthreads();
  int last = lsum[bb] - 1; if (last < 0) last = 0;

  const unsigned short* gib = gi + (size_t)(brow0 + bb) * SSL * G3;
  unsigned short ur0 = gib[(size_t)0 * G3 + 0 * HH + jp];
  unsigned short uz0 = gib[(size_t)0 * G3 + 1 * HH + jp];
  unsigned short un0 = gib[(size_t)0 * G3 + 2 * HH + jp];
  unsigned short ur1 = gib[(size_t)1 * G3 + 0 * HH + jp];
  unsigned short uz1 = gib[(size_t)1 * G3 + 1 * HH + jp];
  unsigned short un1 = gib[(size_t)1 * G3 + 2 * HH + jp];

  auto step = [&](int t, unsigned short& ur, unsigned short& uz, unsigned short& un) {
    const int cb = t & 1, nb = cb ^ 1;
    // capture this step's gi before re-loading the regs
    float girf = bf2f(ur), gizf = bf2f(uz), ginf = bf2f(un);
    // ---- phase A: gh = Whh . h (MFMA, B cols broadcast over n16&3) ----
    f32x4 acc[3];
#pragma unroll
    for (int g = 0; g < 3; g++) acc[g] = f32x4{0.f, 0.f, 0.f, 0.f};
#pragma unroll
    for (int kt = 0; kt < 8; kt++) {
      short8 hb = *(const short8*)&hfrag[cb][kt][n16 & 3][quad][0];
#pragma unroll
      for (int g = 0; g < 3; g++)
        acc[g] = __builtin_amdgcn_mfma_f32_16x16x32_bf16(aw[g][kt], hb, acc[g], 0, 0, 0);
    }
    if (n16 < 4) {
#pragma unroll
      for (int g = 0; g < 3; g++)
        *(f32x4*)&pre[g][n16][w * 16 + quad * 4] = acc[g];
    }
    // prefetch gi for t+2 (stays in flight across the lgkm-only barriers)
    int tn = (t + 2 < SSL) ? t + 2 : SSL - 1;
    ur = gib[(size_t)tn * G3 + 0 * HH + jp];
    uz = gib[(size_t)tn * G3 + 1 * HH + jp];
    un = gib[(size_t)tn * G3 + 2 * HH + jp];
    block_sync_lds();
    // ---- phase B: gates + state update (1 element/thread, fp32) ----
    float gr = pre[0][bb][jp] + bhr + girf;
    float gz = pre[1][bb][jp] + bhz + gizf;
    float hn = pre[2][bb][jp] + bhn;
    float r = __builtin_amdgcn_rcpf(1.f + __expf(-gr));
    float z = __builtin_amdgcn_rcpf(1.f + __expf(-gz));
    float a = ginf + r * hn;
    float n = 1.f - 2.f * __builtin_amdgcn_rcpf(__expf(2.f * a) + 1.f);
    float hN = n + z * (h_old - n);
    h_old = hN;
    hfrag[nb][jp >> 5][bb][(jp >> 3) & 3][jp & 7] = f2bf(hN);
    if (t == last) out[(size_t)(brow0 + bb) * HH + jp] = hN;
    block_sync_lds();
  };

  for (int t = 0; t < SSL; t += 2) {
    step(t, ur0, uz0, un0);
    step(t + 1, ur1, uz1, un1);
  }
}

extern "C" void kernel_launch(void* const* d_in, const int* in_sizes, int n_in,
                              void* d_out, int out_size, void* d_ws, size_t ws_size,
                              hipStream_t stream) {
  const float* tree = (const float*)d_in[0];
  const float* seq  = (const float*)d_in[1];
  const int*   mask = (const int*)d_in[2];
  const float* Wih  = (const float*)d_in[3];
  const float* Whh  = (const float*)d_in[4];
  const float* bih  = (const float*)d_in[5];
  const float* bhh  = (const float*)d_in[6];
  float* out = (float*)d_out;
  unsigned short* gi = (unsigned short*)d_ws;  // 256*512*768 bf16 = 201.3 MB

  gi_gemm<<<dim3(6, 1024), 512, 0, stream>>>(seq, Wih, bih, gi);
  gru_scan<<<dim3(64), 1024, 0, stream>>>(tree, mask, Whh, bhh, gi, out);
}

// Round 4
// 1062.189 us; speedup vs baseline: 1.7013x; 1.7013x over previous
//
#include <hip/hip_runtime.h>
#include <hip/hip_bf16.h>

#define HH 256
#define SSL 512
#define G3 768

using short8 = __attribute__((ext_vector_type(8))) short;
using f32x4  = __attribute__((ext_vector_type(4))) float;

__device__ __forceinline__ unsigned short f2bf(float f) {
  unsigned int u = __float_as_uint(f);
  u += 0x7FFFu + ((u >> 16) & 1u);
  return (unsigned short)(u >> 16);
}
__device__ __forceinline__ float bf2f(unsigned short b) {
  return __uint_as_float(((unsigned int)b) << 16);
}
// barrier that does NOT drain vmcnt (keeps global prefetch in flight)
__device__ __forceinline__ void block_sync_lds() {
  asm volatile("s_waitcnt lgkmcnt(0)\n\ts_barrier" ::: "memory");
}

// ---------------------------------------------------------------------------
// Prep: pack W_ih -> bf16 [j][k] rows; W_hh -> bf16 MFMA-fragment image so the
// scan loads each A-fragment as one global_load_dwordx4 (zero per-step VALU).
// Fragment id F(w,g,mt,kt) = ((w*3+g)*2+mt)*8+kt ; frag data = 64 lanes x 16B.
// ---------------------------------------------------------------------------
__global__ __launch_bounds__(256) void prep_pack(
    const float* __restrict__ Wih, const float* __restrict__ Whh,
    unsigned short* __restrict__ wih_bf, unsigned short* __restrict__ whh_frag)
{
  int blk = blockIdx.x;
  if (blk < 96) {
    int base = (blk * 256 + threadIdx.x) * 4;
#pragma unroll
    for (int i = 0; i < 4; i++) {
      int u = base + i;                      // 0..98303 u32-pairs
      float a = Wih[2 * u], b = Wih[2 * u + 1];
      ((unsigned int*)wih_bf)[u] = (unsigned int)f2bf(a) | ((unsigned int)f2bf(b) << 16);
    }
  } else {
    int gid = (blk - 96) * 256 + threadIdx.x;  // 0..24575
    int f = gid >> 6, l = gid & 63;
    int kt = f & 7, mt = (f >> 3) & 1, g = (f >> 4) % 3, w = f / 48;
    int row = g * HH + w * 32 + mt * 16 + (l & 15);
    int k0  = kt * 32 + (l >> 4) * 8;
    const float* src = Whh + (size_t)row * HH + k0;
    unsigned int o[4];
#pragma unroll
    for (int i = 0; i < 4; i++)
      o[i] = (unsigned int)f2bf(src[2 * i]) | ((unsigned int)f2bf(src[2 * i + 1]) << 16);
    *(uint4*)(whh_frag + ((size_t)f * 64 + l) * 8) = *(uint4*)o;
  }
}

// ---------------------------------------------------------------------------
// Kernel 1: GI[b][s][j] = sum_h X[b][h][s]*Wih[j][h] + bih[j]  (bf16 out)
// grid (6,1024): j-blocks sharing an X tile are dispatch-adjacent (L2 reuse).
// LDS tiles: dense 128B rows, chunk position XOR-swizzled by (r+(r>>3))&7 so
// frag ds_read_b128 hits distinct banks (2-way max = free); staging is
// b128 copies (B) / round-to-nearest bf16 packs (A).
// ---------------------------------------------------------------------------
__global__ __launch_bounds__(512, 4) void gi_gemm(
    const float* __restrict__ X, const unsigned short* __restrict__ Wb,
    const float* __restrict__ bih, unsigned short* __restrict__ gi)
{
  __shared__ __align__(16) char smem[36864];
  unsigned short* Al = (unsigned short*)smem;            // 128 rows x 64 shorts
  unsigned short* Bl = (unsigned short*)(smem + 16384);  // 128 rows x 64 shorts
  float (*Dl)[132] = (float(*)[132])smem;                // epilogue reuse

  const int tid  = threadIdx.x;
  const int lane = tid & 63;
  const int wave = tid >> 6;
  const int wm   = wave >> 2;
  const int wj   = wave & 3;
  const int n16  = lane & 15;
  const int quad = lane >> 4;

  const int mblk = blockIdx.y;
  const int b    = mblk >> 2;
  const int s0   = (mblk & 3) * 128;
  const int j0   = blockIdx.x * 128;

  f32x4 acc[4][2];
#pragma unroll
  for (int mt = 0; mt < 4; mt++)
#pragma unroll
    for (int jt = 0; jt < 2; jt++) acc[mt][jt] = f32x4{0.f, 0.f, 0.f, 0.f};

  const float* Xb = X + (size_t)b * (HH * SSL);

  float4 xa[2][2];   // [pass][h parity]
  uint4  wbv[2];     // B chunks

  auto ldA = [&](int kt, int q, float4* dst) {
    int idx = tid + 512 * q, sq = idx & 31, a = idx >> 5;
    const float* p = Xb + (size_t)(kt * 64 + 2 * a) * SSL + s0 + 4 * sq;
    dst[0] = *(const float4*)p;
    dst[1] = *(const float4*)(p + SSL);
  };
  auto ldB = [&](int kt, int q) -> uint4 {
    int cid = tid + 512 * q, j = cid >> 3, c = cid & 7;
    return *(const uint4*)(Wb + (size_t)(j0 + j) * HH + kt * 64 + c * 8);
  };

  ldA(0, 0, xa[0]); ldA(0, 1, xa[1]);
  wbv[0] = ldB(0, 0); wbv[1] = ldB(0, 1);

  for (int kt = 0; kt < 4; kt++) {
    // stage A: round-to-nearest bf16 pack of an h-pair (even=lo, odd=hi)
#pragma unroll
    for (int q = 0; q < 2; q++) {
      int idx = tid + 512 * q, sq = idx & 31, a = idx >> 5;
      int c = a >> 2, d = a & 3;
#pragma unroll
      for (int r = 0; r < 4; r++) {
        int s = 4 * sq + r;
        int sw = (s + (s >> 3)) & 7;
        unsigned int u =
            (unsigned int)f2bf(((const float*)&xa[q][0])[r]) |
            ((unsigned int)f2bf(((const float*)&xa[q][1])[r]) << 16);
        *(unsigned int*)(Al + s * 64 + ((c ^ sw) * 8) + d * 2) = u;
      }
    }
    // stage B: straight b128 copy into swizzled chunk
#pragma unroll
    for (int p = 0; p < 2; p++) {
      int cid = tid + 512 * p, j = cid >> 3, c = cid & 7;
      int sw = (j + (j >> 3)) & 7;
      *(uint4*)(Bl + j * 64 + ((c ^ sw) * 8)) = wbv[p];
    }
    __syncthreads();
    if (kt < 3) {
      ldA(kt + 1, 0, xa[0]); ldA(kt + 1, 1, xa[1]);
      wbv[0] = ldB(kt + 1, 0); wbv[1] = ldB(kt + 1, 1);
    }
#pragma unroll
    for (int kk = 0; kk < 2; kk++) {
      short8 af[4], bfr[2];
#pragma unroll
      for (int mt = 0; mt < 4; mt++) {
        int s = wm * 64 + mt * 16 + n16;
        int sw = (s + (s >> 3)) & 7;
        af[mt] = *(const short8*)(Al + s * 64 + (((kk * 4 + quad) ^ sw) * 8));
      }
#pragma unroll
      for (int jt = 0; jt < 2; jt++) {
        int j = wj * 32 + jt * 16 + n16;
        int sw = (j + (j >> 3)) & 7;
        bfr[jt] = *(const short8*)(Bl + j * 64 + (((kk * 4 + quad) ^ sw) * 8));
      }
#pragma unroll
      for (int mt = 0; mt < 4; mt++)
#pragma unroll
        for (int jt = 0; jt < 2; jt++)
          acc[mt][jt] = __builtin_amdgcn_mfma_f32_16x16x32_bf16(af[mt], bfr[jt], acc[mt][jt], 0, 0, 0);
    }
    __syncthreads();
  }

  float bias[2];
  bias[0] = bih[j0 + wj * 32 + 0 * 16 + n16];
  bias[1] = bih[j0 + wj * 32 + 1 * 16 + n16];

  for (int c = 0; c < 2; c++) {
    __syncthreads();
    if (wm == c) {
#pragma unroll
      for (int mt = 0; mt < 4; mt++)
#pragma unroll
        for (int jt = 0; jt < 2; jt++)
#pragma unroll
          for (int r = 0; r < 4; r++)
            Dl[mt * 16 + quad * 4 + r][wj * 32 + jt * 16 + n16] = acc[mt][jt][r] + bias[jt];
    }
    __syncthreads();
#pragma unroll
    for (int i = 0; i < 2; i++) {
      int ml = (tid >> 4) + 32 * i;
      int jj = (tid & 15) * 8;
      float4 p0 = *(const float4*)&Dl[ml][jj];
      float4 p1 = *(const float4*)&Dl[ml][jj + 4];
      short8 st;
      st[0] = (short)f2bf(p0.x); st[1] = (short)f2bf(p0.y);
      st[2] = (short)f2bf(p0.z); st[3] = (short)f2bf(p0.w);
      st[4] = (short)f2bf(p1.x); st[5] = (short)f2bf(p1.y);
      st[6] = (short)f2bf(p1.z); st[7] = (short)f2bf(p1.w);
      int sgl = s0 + c * 64 + ml;
      *(short8*)(gi + ((size_t)b * SSL + sgl) * G3 + j0 + jj) = st;
    }
  }
}

// ---------------------------------------------------------------------------
// Kernel 2: persistent GRU scan. 64 blocks x 4 rows, 512 thr (8 waves).
// Wave w owns j-rows {g*256 + w*32 + mt*16 + n16}. 48 frags/wave: 42 in regs
// (168 VGPR, pinned; cap 256 via launch_bounds(512,2)) + 6 (g=2,kt 5..7) in
// LDS. Frags come pre-packed: one dwordx4 each, zero cvt VALU per step.
// LDS budget exactly 64 KB: wlds 48K + hfrag 4K + pre 12K (lsum aliases pre,
// so `last` must be read BEFORE the loop with a barrier after the read —
// R3's missing barrier here was the correctness bug).
// ---------------------------------------------------------------------------
__global__ __launch_bounds__(512, 2) void gru_scan(
    const float* __restrict__ tree, const int* __restrict__ mask,
    const unsigned short* __restrict__ wfrag, const float* __restrict__ bhh,
    const unsigned short* __restrict__ gi, float* __restrict__ out)
{
  __shared__ __align__(16) unsigned char lds[65536];
  unsigned short* wlds = (unsigned short*)lds;                      // 49152 B
  unsigned short (*hfrag)[8][4][4][8] =
      (unsigned short(*)[8][4][4][8])(lds + 49152);                 // 2 x 2048 B
  float* preF = (float*)(lds + 53248);                              // 3*4*256 f32
  int*   lsum = (int*)(lds + 53248);                                // aliases preF

  const int tid  = threadIdx.x;
  const int lane = tid & 63;
  const int w    = tid >> 6;
  const int n16  = lane & 15;
  const int quad = lane >> 4;
  const int brow0 = blockIdx.x * 4;
  const int bb = tid >> 7;           // 0..3
  const int jj = (tid & 127) * 2;    // even j

  if (tid < 4) lsum[tid] = 0;
  // stage the 6 LDS frags per wave: g=2, mt 0..1, kt 5..7
#pragma unroll
  for (int i = 0; i < 6; i++) {
    int cid = tid + 512 * i;         // 0..3071
    int l = cid & 63, rest = cid >> 6;
    int ktp = rest % 3, mtp = (rest / 3) & 1, wp = rest / 6;
    int F = ((wp * 3 + 2) * 2 + mtp) * 8 + (5 + ktp);
    uint4 v = *(const uint4*)(wfrag + ((size_t)F * 64 + l) * 8);
    *(uint4*)(wlds + (((size_t)(wp * 2 + mtp) * 3 + ktp) * 64 + l) * 8) = v;
  }
  __syncthreads();
  {
    const int* mp = mask + (size_t)(brow0 + bb) * SSL + (tid & 127) * 4;
    atomicAdd(&lsum[bb], mp[0] + mp[1] + mp[2] + mp[3]);
  }

  // register-resident frags: g 0..1 all kt (32) + g=2 kt 0..4 (10) = 42
  short8 aw[2][2][8];
#pragma unroll
  for (int g = 0; g < 2; g++)
#pragma unroll
    for (int mt = 0; mt < 2; mt++)
#pragma unroll
      for (int kt = 0; kt < 8; kt++) {
        int F = ((w * 3 + g) * 2 + mt) * 8 + kt;
        aw[g][mt][kt] = *(const short8*)(wfrag + ((size_t)F * 64 + lane) * 8);
      }
  short8 aw2[2][5];
#pragma unroll
  for (int mt = 0; mt < 2; mt++)
#pragma unroll
    for (int kt = 0; kt < 5; kt++) {
      int F = ((w * 3 + 2) * 2 + mt) * 8 + kt;
      aw2[mt][kt] = *(const short8*)(wfrag + ((size_t)F * 64 + lane) * 8);
    }
#pragma unroll
  for (int g = 0; g < 2; g++)
#pragma unroll
    for (int mt = 0; mt < 2; mt++)
#pragma unroll
      for (int kt = 0; kt < 8; kt++)
        asm volatile("" : "+v"(aw[g][mt][kt]));
#pragma unroll
  for (int mt = 0; mt < 2; mt++)
#pragma unroll
    for (int kt = 0; kt < 5; kt++)
      asm volatile("" : "+v"(aw2[mt][kt]));

  float bhr0 = bhh[jj],        bhr1 = bhh[jj + 1];
  float bhz0 = bhh[HH + jj],   bhz1 = bhh[HH + jj + 1];
  float bhn0 = bhh[2*HH + jj], bhn1 = bhh[2*HH + jj + 1];

  float h0 = tree[(size_t)(brow0 + bb) * HH + jj];
  float h1 = tree[(size_t)(brow0 + bb) * HH + jj + 1];
  *(unsigned int*)&hfrag[0][jj >> 5][bb][(jj >> 3) & 3][jj & 7] =
      (unsigned int)f2bf(h0) | ((unsigned int)f2bf(h1) << 16);
  __syncthreads();
  int last = lsum[bb] - 1; if (last < 0) last = 0;
  // CRITICAL: lsum aliases preF; every thread must read lsum before ANY
  // wave enters step 0 and overwrites preF[0..3]. (R3 bug.)
  __syncthreads();

  const unsigned short* gib = gi + (size_t)(brow0 + bb) * SSL * G3;
  unsigned int giA[3], giB[3];
#pragma unroll
  for (int g = 0; g < 3; g++) giA[g] = *(const unsigned int*)(gib + (size_t)0 * G3 + g * HH + jj);
#pragma unroll
  for (int g = 0; g < 3; g++) giB[g] = *(const unsigned int*)(gib + (size_t)1 * G3 + g * HH + jj);

  auto step = [&](int t, unsigned int* gv) {
    const int cb = t & 1, nb = cb ^ 1;
    float gir0 = bf2f((unsigned short)(gv[0] & 0xFFFF)), gir1 = bf2f((unsigned short)(gv[0] >> 16));
    float giz0 = bf2f((unsigned short)(gv[1] & 0xFFFF)), giz1 = bf2f((unsigned short)(gv[1] >> 16));
    float gin0 = bf2f((unsigned short)(gv[2] & 0xFFFF)), gin1 = bf2f((unsigned short)(gv[2] >> 16));

    f32x4 acc[3][2];
#pragma unroll
    for (int g = 0; g < 3; g++)
#pragma unroll
      for (int mt = 0; mt < 2; mt++) acc[g][mt] = f32x4{0.f, 0.f, 0.f, 0.f};
#pragma unroll
    for (int kt = 0; kt < 8; kt++) {
      short8 hb = *(const short8*)&hfrag[cb][kt][n16 & 3][quad][0];
#pragma unroll
      for (int mt = 0; mt < 2; mt++) {
        acc[0][mt] = __builtin_amdgcn_mfma_f32_16x16x32_bf16(aw[0][mt][kt], hb, acc[0][mt], 0, 0, 0);
        acc[1][mt] = __builtin_amdgcn_mfma_f32_16x16x32_bf16(aw[1][mt][kt], hb, acc[1][mt], 0, 0, 0);
        short8 w2 = (kt < 5) ? aw2[mt][kt]
                  : *(const short8*)(wlds + (((size_t)(w * 2 + mt) * 3 + (kt - 5)) * 64 + lane) * 8);
        acc[2][mt] = __builtin_amdgcn_mfma_f32_16x16x32_bf16(w2, hb, acc[2][mt], 0, 0, 0);
      }
    }
    if (n16 < 4) {
#pragma unroll
      for (int g = 0; g < 3; g++)
#pragma unroll
        for (int mt = 0; mt < 2; mt++)
          *(f32x4*)(preF + g * 1024 + n16 * 256 + w * 32 + mt * 16 + quad * 4) = acc[g][mt];
    }
    int tn = (t + 2 < SSL) ? t + 2 : SSL - 1;
    gv[0] = *(const unsigned int*)(gib + (size_t)tn * G3 + 0 * HH + jj);
    gv[1] = *(const unsigned int*)(gib + (size_t)tn * G3 + 1 * HH + jj);
    gv[2] = *(const unsigned int*)(gib + (size_t)tn * G3 + 2 * HH + jj);
    block_sync_lds();

    float hr0 = preF[0*1024 + bb*256 + jj]     + bhr0 + gir0;
    float hr1 = preF[0*1024 + bb*256 + jj + 1] + bhr1 + gir1;
    float hz0 = preF[1*1024 + bb*256 + jj]     + bhz0 + giz0;
    float hz1 = preF[1*1024 + bb*256 + jj + 1] + bhz1 + giz1;
    float hn0 = preF[2*1024 + bb*256 + jj]     + bhn0;
    float hn1 = preF[2*1024 + bb*256 + jj + 1] + bhn1;
    float r0 = __builtin_amdgcn_rcpf(1.f + __expf(-hr0));
    float r1 = __builtin_amdgcn_rcpf(1.f + __expf(-hr1));
    float z0 = __builtin_amdgcn_rcpf(1.f + __expf(-hz0));
    float z1 = __builtin_amdgcn_rcpf(1.f + __expf(-hz1));
    float a0 = gin0 + r0 * hn0, a1 = gin1 + r1 * hn1;
    float nn0 = 1.f - 2.f * __builtin_amdgcn_rcpf(__expf(2.f * a0) + 1.f);
    float nn1 = 1.f - 2.f * __builtin_amdgcn_rcpf(__expf(2.f * a1) + 1.f);
    float hN0 = nn0 + z0 * (h0 - nn0);
    float hN1 = nn1 + z1 * (h1 - nn1);
    h0 = hN0; h1 = hN1;
    *(unsigned int*)&hfrag[nb][jj >> 5][bb][(jj >> 3) & 3][jj & 7] =
        (unsigned int)f2bf(hN0) | ((unsigned int)f2bf(hN1) << 16);
    if (t == last) {
      out[(size_t)(brow0 + bb) * HH + jj] = hN0;
      out[(size_t)(brow0 + bb) * HH + jj + 1] = hN1;
    }
    block_sync_lds();
  };

  for (int t = 0; t < SSL; t += 2) {
    step(t, giA);
    step(t + 1, giB);
  }
}

extern "C" void kernel_launch(void* const* d_in, const int* in_sizes, int n_in,
                              void* d_out, int out_size, void* d_ws, size_t ws_size,
                              hipStream_t stream) {
  const float* tree = (const float*)d_in[0];
  const float* seq  = (const float*)d_in[1];
  const int*   mask = (const int*)d_in[2];
  const float* Wih  = (const float*)d_in[3];
  const float* Whh  = (const float*)d_in[4];
  const float* bih  = (const float*)d_in[5];
  const float* bhh  = (const float*)d_in[6];
  float* out = (float*)d_out;

  unsigned short* gi      = (unsigned short*)d_ws;                       // 201,326,592 B
  unsigned short* wih_bf  = (unsigned short*)((char*)d_ws + 201326592);  // 393,216 B
  unsigned short* whh_frag= (unsigned short*)((char*)d_ws + 201719808);  // 393,216 B

  prep_pack<<<192, 256, 0, stream>>>(Wih, Whh, wih_bf, whh_frag);
  gi_gemm<<<dim3(6, 1024), 512, 0, stream>>>(seq, wih_bf, bih, gi);
  gru_scan<<<64, 512, 0, stream>>>(tree, mask, whh_frag, bhh, gi, out);
}

// Round 5
// 1021.480 us; speedup vs baseline: 1.7691x; 1.0399x over previous
//
#include <hip/hip_runtime.h>
#include <hip/hip_bf16.h>

#define HH 256
#define SSL 512
#define G3 768

using short8 = __attribute__((ext_vector_type(8))) short;
using f32x4  = __attribute__((ext_vector_type(4))) float;

__device__ __forceinline__ unsigned short f2bf(float f) {
  unsigned int u = __float_as_uint(f);
  u += 0x7FFFu + ((u >> 16) & 1u);
  return (unsigned short)(u >> 16);
}
__device__ __forceinline__ float bf2f(unsigned short b) {
  return __uint_as_float(((unsigned int)b) << 16);
}
// barrier that does NOT drain vmcnt (keeps global prefetch in flight)
__device__ __forceinline__ void block_sync_lds() {
  asm volatile("s_waitcnt lgkmcnt(0)\n\ts_barrier" ::: "memory");
}

// ---------------------------------------------------------------------------
// Prep: pack W_ih -> bf16 [j][k] rows; W_hh -> bf16 MFMA-fragment image so the
// scan loads each A-fragment as one global_load_dwordx4 (zero per-step VALU).
// Fragment id F(w,g,mt,kt) = ((w*3+g)*2+mt)*8+kt ; frag data = 64 lanes x 16B.
// ---------------------------------------------------------------------------
__global__ __launch_bounds__(256) void prep_pack(
    const float* __restrict__ Wih, const float* __restrict__ Whh,
    unsigned short* __restrict__ wih_bf, unsigned short* __restrict__ whh_frag)
{
  int blk = blockIdx.x;
  if (blk < 96) {
    int base = (blk * 256 + threadIdx.x) * 4;
#pragma unroll
    for (int i = 0; i < 4; i++) {
      int u = base + i;                      // 0..98303 u32-pairs
      float a = Wih[2 * u], b = Wih[2 * u + 1];
      ((unsigned int*)wih_bf)[u] = (unsigned int)f2bf(a) | ((unsigned int)f2bf(b) << 16);
    }
  } else {
    int gid = (blk - 96) * 256 + threadIdx.x;  // 0..24575
    int f = gid >> 6, l = gid & 63;
    int kt = f & 7, mt = (f >> 3) & 1, g = (f >> 4) % 3, w = f / 48;
    int row = g * HH + w * 32 + mt * 16 + (l & 15);
    int k0  = kt * 32 + (l >> 4) * 8;
    const float* src = Whh + (size_t)row * HH + k0;
    unsigned int o[4];
#pragma unroll
    for (int i = 0; i < 4; i++)
      o[i] = (unsigned int)f2bf(src[2 * i]) | ((unsigned int)f2bf(src[2 * i + 1]) << 16);
    *(uint4*)(whh_frag + ((size_t)f * 64 + l) * 8) = *(uint4*)o;
  }
}

// ---------------------------------------------------------------------------
// Kernel 1: GI[b][s][j] = sum_h X[b][h][s]*Wih[j][h] + bih[j]  (bf16 out)
// grid (6,1024): j-blocks sharing an X tile are dispatch-adjacent (L2 reuse).
// LDS tiles: dense 128B rows, chunk position XOR-swizzled by (r+(r>>3))&7 so
// frag ds_read_b128 hits distinct banks (2-way max = free); staging is
// b128 copies (B) / round-to-nearest bf16 packs (A).
// ---------------------------------------------------------------------------
__global__ __launch_bounds__(512, 4) void gi_gemm(
    const float* __restrict__ X, const unsigned short* __restrict__ Wb,
    const float* __restrict__ bih, unsigned short* __restrict__ gi)
{
  __shared__ __align__(16) char smem[36864];
  unsigned short* Al = (unsigned short*)smem;            // 128 rows x 64 shorts
  unsigned short* Bl = (unsigned short*)(smem + 16384);  // 128 rows x 64 shorts
  float (*Dl)[132] = (float(*)[132])smem;                // epilogue reuse

  const int tid  = threadIdx.x;
  const int lane = tid & 63;
  const int wave = tid >> 6;
  const int wm   = wave >> 2;
  const int wj   = wave & 3;
  const int n16  = lane & 15;
  const int quad = lane >> 4;

  const int mblk = blockIdx.y;
  const int b    = mblk >> 2;
  const int s0   = (mblk & 3) * 128;
  const int j0   = blockIdx.x * 128;

  f32x4 acc[4][2];
#pragma unroll
  for (int mt = 0; mt < 4; mt++)
#pragma unroll
    for (int jt = 0; jt < 2; jt++) acc[mt][jt] = f32x4{0.f, 0.f, 0.f, 0.f};

  const float* Xb = X + (size_t)b * (HH * SSL);

  float4 xa[2][2];   // [pass][h parity]
  uint4  wbv[2];     // B chunks

  auto ldA = [&](int kt, int q, float4* dst) {
    int idx = tid + 512 * q, sq = idx & 31, a = idx >> 5;
    const float* p = Xb + (size_t)(kt * 64 + 2 * a) * SSL + s0 + 4 * sq;
    dst[0] = *(const float4*)p;
    dst[1] = *(const float4*)(p + SSL);
  };
  auto ldB = [&](int kt, int q) -> uint4 {
    int cid = tid + 512 * q, j = cid >> 3, c = cid & 7;
    return *(const uint4*)(Wb + (size_t)(j0 + j) * HH + kt * 64 + c * 8);
  };

  ldA(0, 0, xa[0]); ldA(0, 1, xa[1]);
  wbv[0] = ldB(0, 0); wbv[1] = ldB(0, 1);

  for (int kt = 0; kt < 4; kt++) {
    // stage A: round-to-nearest bf16 pack of an h-pair (even=lo, odd=hi)
#pragma unroll
    for (int q = 0; q < 2; q++) {
      int idx = tid + 512 * q, sq = idx & 31, a = idx >> 5;
      int c = a >> 2, d = a & 3;
#pragma unroll
      for (int r = 0; r < 4; r++) {
        int s = 4 * sq + r;
        int sw = (s + (s >> 3)) & 7;
        unsigned int u =
            (unsigned int)f2bf(((const float*)&xa[q][0])[r]) |
            ((unsigned int)f2bf(((const float*)&xa[q][1])[r]) << 16);
        *(unsigned int*)(Al + s * 64 + ((c ^ sw) * 8) + d * 2) = u;
      }
    }
    // stage B: straight b128 copy into swizzled chunk
#pragma unroll
    for (int p = 0; p < 2; p++) {
      int cid = tid + 512 * p, j = cid >> 3, c = cid & 7;
      int sw = (j + (j >> 3)) & 7;
      *(uint4*)(Bl + j * 64 + ((c ^ sw) * 8)) = wbv[p];
    }
    __syncthreads();
    if (kt < 3) {
      ldA(kt + 1, 0, xa[0]); ldA(kt + 1, 1, xa[1]);
      wbv[0] = ldB(kt + 1, 0); wbv[1] = ldB(kt + 1, 1);
    }
#pragma unroll
    for (int kk = 0; kk < 2; kk++) {
      short8 af[4], bfr[2];
#pragma unroll
      for (int mt = 0; mt < 4; mt++) {
        int s = wm * 64 + mt * 16 + n16;
        int sw = (s + (s >> 3)) & 7;
        af[mt] = *(const short8*)(Al + s * 64 + (((kk * 4 + quad) ^ sw) * 8));
      }
#pragma unroll
      for (int jt = 0; jt < 2; jt++) {
        int j = wj * 32 + jt * 16 + n16;
        int sw = (j + (j >> 3)) & 7;
        bfr[jt] = *(const short8*)(Bl + j * 64 + (((kk * 4 + quad) ^ sw) * 8));
      }
#pragma unroll
      for (int mt = 0; mt < 4; mt++)
#pragma unroll
        for (int jt = 0; jt < 2; jt++)
          acc[mt][jt] = __builtin_amdgcn_mfma_f32_16x16x32_bf16(af[mt], bfr[jt], acc[mt][jt], 0, 0, 0);
    }
    __syncthreads();
  }

  float bias[2];
  bias[0] = bih[j0 + wj * 32 + 0 * 16 + n16];
  bias[1] = bih[j0 + wj * 32 + 1 * 16 + n16];

  for (int c = 0; c < 2; c++) {
    __syncthreads();
    if (wm == c) {
#pragma unroll
      for (int mt = 0; mt < 4; mt++)
#pragma unroll
        for (int jt = 0; jt < 2; jt++)
#pragma unroll
          for (int r = 0; r < 4; r++)
            Dl[mt * 16 + quad * 4 + r][wj * 32 + jt * 16 + n16] = acc[mt][jt][r] + bias[jt];
    }
    __syncthreads();
#pragma unroll
    for (int i = 0; i < 2; i++) {
      int ml = (tid >> 4) + 32 * i;
      int jj = (tid & 15) * 8;
      float4 p0 = *(const float4*)&Dl[ml][jj];
      float4 p1 = *(const float4*)&Dl[ml][jj + 4];
      short8 st;
      st[0] = (short)f2bf(p0.x); st[1] = (short)f2bf(p0.y);
      st[2] = (short)f2bf(p0.z); st[3] = (short)f2bf(p0.w);
      st[4] = (short)f2bf(p1.x); st[5] = (short)f2bf(p1.y);
      st[6] = (short)f2bf(p1.z); st[7] = (short)f2bf(p1.w);
      int sgl = s0 + c * 64 + ml;
      *(short8*)(gi + ((size_t)b * SSL + sgl) * G3 + j0 + jj) = st;
    }
  }
}

// ---------------------------------------------------------------------------
// Kernel 2: persistent GRU scan. 64 blocks x 4 rows, 512 thr (8 waves).
// KEY (R4 post-mortem): LDS is declared 84 KB (> 80 KB) so the compiler's
// LDS-derived occupancy is 1 block/CU = 2 waves/EU -> register budget
// 256/wave, letting the 42 pinned W fragments (168 VGPR) actually live in
// registers instead of spilling to scratch (R4: 64 KB LDS -> 4 waves/EU ->
// 128-reg cap -> scratch refill ~672 B/lane/step). Runtime occupancy is
// unchanged: 64 blocks on 256 CUs was already 1 block/CU.
// preF row stride 264 floats: n16 stride = 1056 B ≡ 8 banks -> worst 2-way
// (free) instead of R4's 4-way. lsum has its own LDS (no aliasing hazards).
// ---------------------------------------------------------------------------
__global__ __launch_bounds__(512, 1) void gru_scan(
    const float* __restrict__ tree, const int* __restrict__ mask,
    const unsigned short* __restrict__ wfrag, const float* __restrict__ bhh,
    const unsigned short* __restrict__ gi, float* __restrict__ out)
{
  __shared__ __align__(16) unsigned char lds[86016];  // 84 KB: forces 1 blk/CU
  unsigned short* wlds = (unsigned short*)lds;                      // 49152 B
  unsigned short (*hfrag)[8][4][4][8] =
      (unsigned short(*)[8][4][4][8])(lds + 49152);                 // 2 x 2048 B
  float* preF = (float*)(lds + 53248);   // [g][n16][264] f32 = 12672 B
  int*   lsum = (int*)(lds + 65920);     // 16 B, dedicated

  const int tid  = threadIdx.x;
  const int lane = tid & 63;
  const int w    = tid >> 6;
  const int n16  = lane & 15;
  const int quad = lane >> 4;
  const int brow0 = blockIdx.x * 4;
  const int bb = tid >> 7;           // 0..3
  const int jj = (tid & 127) * 2;    // even j

  if (tid < 4) lsum[tid] = 0;
  // stage the 6 LDS frags per wave: g=2, mt 0..1, kt 5..7
#pragma unroll
  for (int i = 0; i < 6; i++) {
    int cid = tid + 512 * i;         // 0..3071
    int l = cid & 63, rest = cid >> 6;
    int ktp = rest % 3, mtp = (rest / 3) & 1, wp = rest / 6;
    int F = ((wp * 3 + 2) * 2 + mtp) * 8 + (5 + ktp);
    uint4 v = *(const uint4*)(wfrag + ((size_t)F * 64 + l) * 8);
    *(uint4*)(wlds + (((size_t)(wp * 2 + mtp) * 3 + ktp) * 64 + l) * 8) = v;
  }
  __syncthreads();
  {
    const int* mp = mask + (size_t)(brow0 + bb) * SSL + (tid & 127) * 4;
    atomicAdd(&lsum[bb], mp[0] + mp[1] + mp[2] + mp[3]);
  }

  // register-resident frags: g 0..1 all kt (32) + g=2 kt 0..4 (10) = 42
  short8 aw[2][2][8];
#pragma unroll
  for (int g = 0; g < 2; g++)
#pragma unroll
    for (int mt = 0; mt < 2; mt++)
#pragma unroll
      for (int kt = 0; kt < 8; kt++) {
        int F = ((w * 3 + g) * 2 + mt) * 8 + kt;
        aw[g][mt][kt] = *(const short8*)(wfrag + ((size_t)F * 64 + lane) * 8);
      }
  short8 aw2[2][5];
#pragma unroll
  for (int mt = 0; mt < 2; mt++)
#pragma unroll
    for (int kt = 0; kt < 5; kt++) {
      int F = ((w * 3 + 2) * 2 + mt) * 8 + kt;
      aw2[mt][kt] = *(const short8*)(wfrag + ((size_t)F * 64 + lane) * 8);
    }
#pragma unroll
  for (int g = 0; g < 2; g++)
#pragma unroll
    for (int mt = 0; mt < 2; mt++)
#pragma unroll
      for (int kt = 0; kt < 8; kt++)
        asm volatile("" : "+v"(aw[g][mt][kt]));
#pragma unroll
  for (int mt = 0; mt < 2; mt++)
#pragma unroll
    for (int kt = 0; kt < 5; kt++)
      asm volatile("" : "+v"(aw2[mt][kt]));

  float bhr0 = bhh[jj],        bhr1 = bhh[jj + 1];
  float bhz0 = bhh[HH + jj],   bhz1 = bhh[HH + jj + 1];
  float bhn0 = bhh[2*HH + jj], bhn1 = bhh[2*HH + jj + 1];

  float h0 = tree[(size_t)(brow0 + bb) * HH + jj];
  float h1 = tree[(size_t)(brow0 + bb) * HH + jj + 1];
  *(unsigned int*)&hfrag[0][jj >> 5][bb][(jj >> 3) & 3][jj & 7] =
      (unsigned int)f2bf(h0) | ((unsigned int)f2bf(h1) << 16);
  __syncthreads();
  int last = lsum[bb] - 1; if (last < 0) last = 0;

  const unsigned short* gib = gi + (size_t)(brow0 + bb) * SSL * G3;
  unsigned int giA[3], giB[3];
#pragma unroll
  for (int g = 0; g < 3; g++) giA[g] = *(const unsigned int*)(gib + (size_t)0 * G3 + g * HH + jj);
#pragma unroll
  for (int g = 0; g < 3; g++) giB[g] = *(const unsigned int*)(gib + (size_t)1 * G3 + g * HH + jj);

  auto step = [&](int t, unsigned int* gv) {
    const int cb = t & 1, nb = cb ^ 1;
    float gir0 = bf2f((unsigned short)(gv[0] & 0xFFFF)), gir1 = bf2f((unsigned short)(gv[0] >> 16));
    float giz0 = bf2f((unsigned short)(gv[1] & 0xFFFF)), giz1 = bf2f((unsigned short)(gv[1] >> 16));
    float gin0 = bf2f((unsigned short)(gv[2] & 0xFFFF)), gin1 = bf2f((unsigned short)(gv[2] >> 16));

    f32x4 acc[3][2];
#pragma unroll
    for (int g = 0; g < 3; g++)
#pragma unroll
      for (int mt = 0; mt < 2; mt++) acc[g][mt] = f32x4{0.f, 0.f, 0.f, 0.f};
#pragma unroll
    for (int kt = 0; kt < 8; kt++) {
      short8 hb = *(const short8*)&hfrag[cb][kt][n16 & 3][quad][0];
#pragma unroll
      for (int mt = 0; mt < 2; mt++) {
        acc[0][mt] = __builtin_amdgcn_mfma_f32_16x16x32_bf16(aw[0][mt][kt], hb, acc[0][mt], 0, 0, 0);
        acc[1][mt] = __builtin_amdgcn_mfma_f32_16x16x32_bf16(aw[1][mt][kt], hb, acc[1][mt], 0, 0, 0);
        short8 w2 = (kt < 5) ? aw2[mt][kt]
                  : *(const short8*)(wlds + (((size_t)(w * 2 + mt) * 3 + (kt - 5)) * 64 + lane) * 8);
        acc[2][mt] = __builtin_amdgcn_mfma_f32_16x16x32_bf16(w2, hb, acc[2][mt], 0, 0, 0);
      }
    }
    if (n16 < 4) {
#pragma unroll
      for (int g = 0; g < 3; g++)
#pragma unroll
        for (int mt = 0; mt < 2; mt++)
          *(f32x4*)(preF + g * 1056 + n16 * 264 + w * 32 + mt * 16 + quad * 4) = acc[g][mt];
    }
    int tn = (t + 2 < SSL) ? t + 2 : SSL - 1;
    gv[0] = *(const unsigned int*)(gib + (size_t)tn * G3 + 0 * HH + jj);
    gv[1] = *(const unsigned int*)(gib + (size_t)tn * G3 + 1 * HH + jj);
    gv[2] = *(const unsigned int*)(gib + (size_t)tn * G3 + 2 * HH + jj);
    block_sync_lds();

    float2 pr = *(const float2*)(preF + 0 * 1056 + bb * 264 + jj);
    float2 pz = *(const float2*)(preF + 1 * 1056 + bb * 264 + jj);
    float2 pn = *(const float2*)(preF + 2 * 1056 + bb * 264 + jj);
    float hr0 = pr.x + bhr0 + gir0, hr1 = pr.y + bhr1 + gir1;
    float hz0 = pz.x + bhz0 + giz0, hz1 = pz.y + bhz1 + giz1;
    float hn0 = pn.x + bhn0,        hn1 = pn.y + bhn1;
    float r0 = __builtin_amdgcn_rcpf(1.f + __expf(-hr0));
    float r1 = __builtin_amdgcn_rcpf(1.f + __expf(-hr1));
    float z0 = __builtin_amdgcn_rcpf(1.f + __expf(-hz0));
    float z1 = __builtin_amdgcn_rcpf(1.f + __expf(-hz1));
    float a0 = gin0 + r0 * hn0, a1 = gin1 + r1 * hn1;
    float nn0 = 1.f - 2.f * __builtin_amdgcn_rcpf(__expf(2.f * a0) + 1.f);
    float nn1 = 1.f - 2.f * __builtin_amdgcn_rcpf(__expf(2.f * a1) + 1.f);
    float hN0 = nn0 + z0 * (h0 - nn0);
    float hN1 = nn1 + z1 * (h1 - nn1);
    h0 = hN0; h1 = hN1;
    *(unsigned int*)&hfrag[nb][jj >> 5][bb][(jj >> 3) & 3][jj & 7] =
        (unsigned int)f2bf(hN0) | ((unsigned int)f2bf(hN1) << 16);
    if (t == last) {
      out[(size_t)(brow0 + bb) * HH + jj] = hN0;
      out[(size_t)(brow0 + bb) * HH + jj + 1] = hN1;
    }
    block_sync_lds();
  };

  for (int t = 0; t < SSL; t += 2) {
    step(t, giA);
    step(t + 1, giB);
  }
}

extern "C" void kernel_launch(void* const* d_in, const int* in_sizes, int n_in,
                              void* d_out, int out_size, void* d_ws, size_t ws_size,
                              hipStream_t stream) {
  const float* tree = (const float*)d_in[0];
  const float* seq  = (const float*)d_in[1];
  const int*   mask = (const int*)d_in[2];
  const float* Wih  = (const float*)d_in[3];
  const float* Whh  = (const float*)d_in[4];
  const float* bih  = (const float*)d_in[5];
  const float* bhh  = (const float*)d_in[6];
  float* out = (float*)d_out;

  unsigned short* gi      = (unsigned short*)d_ws;                       // 201,326,592 B
  unsigned short* wih_bf  = (unsigned short*)((char*)d_ws + 201326592);  // 393,216 B
  unsigned short* whh_frag= (unsigned short*)((char*)d_ws + 201719808);  // 393,216 B

  prep_pack<<<192, 256, 0, stream>>>(Wih, Whh, wih_bf, whh_frag);
  gi_gemm<<<dim3(6, 1024), 512, 0, stream>>>(seq, wih_bf, bih, gi);
  gru_scan<<<64, 512, 0, stream>>>(tree, mask, whh_frag, bhh, gi, out);
}

// Round 6
// 1001.784 us; speedup vs baseline: 1.8039x; 1.0197x over previous
//
#include <hip/hip_runtime.h>
#include <hip/hip_bf16.h>

#define HH 256
#define SSL 512
#define G3 768

using short8 = __attribute__((ext_vector_type(8))) short;
using f32x4  = __attribute__((ext_vector_type(4))) float;

__device__ __forceinline__ unsigned short f2bf(float f) {
  unsigned int u = __float_as_uint(f);
  u += 0x7FFFu + ((u >> 16) & 1u);
  return (unsigned short)(u >> 16);
}
__device__ __forceinline__ float bf2f(unsigned short b) {
  return __uint_as_float(((unsigned int)b) << 16);
}
// barrier that does NOT drain vmcnt (keeps global prefetch in flight)
__device__ __forceinline__ void block_sync_lds() {
  asm volatile("s_waitcnt lgkmcnt(0)\n\ts_barrier" ::: "memory");
}

// ---------------------------------------------------------------------------
// Prep: pack W_ih -> bf16 [j][k] rows; W_hh -> bf16 MFMA-fragment image so the
// scan loads each A-fragment as one global_load_dwordx4 (zero per-step VALU).
// Fragment id F(w,g,mt,kt) = ((w*3+g)*2+mt)*8+kt ; frag data = 64 lanes x 16B.
// ---------------------------------------------------------------------------
__global__ __launch_bounds__(256) void prep_pack(
    const float* __restrict__ Wih, const float* __restrict__ Whh,
    unsigned short* __restrict__ wih_bf, unsigned short* __restrict__ whh_frag)
{
  int blk = blockIdx.x;
  if (blk < 96) {
    int base = (blk * 256 + threadIdx.x) * 4;
#pragma unroll
    for (int i = 0; i < 4; i++) {
      int u = base + i;                      // 0..98303 u32-pairs
      float a = Wih[2 * u], b = Wih[2 * u + 1];
      ((unsigned int*)wih_bf)[u] = (unsigned int)f2bf(a) | ((unsigned int)f2bf(b) << 16);
    }
  } else {
    int gid = (blk - 96) * 256 + threadIdx.x;  // 0..24575
    int f = gid >> 6, l = gid & 63;
    int kt = f & 7, mt = (f >> 3) & 1, g = (f >> 4) % 3, w = f / 48;
    int row = g * HH + w * 32 + mt * 16 + (l & 15);
    int k0  = kt * 32 + (l >> 4) * 8;
    const float* src = Whh + (size_t)row * HH + k0;
    unsigned int o[4];
#pragma unroll
    for (int i = 0; i < 4; i++)
      o[i] = (unsigned int)f2bf(src[2 * i]) | ((unsigned int)f2bf(src[2 * i + 1]) << 16);
    *(uint4*)(whh_frag + ((size_t)f * 64 + l) * 8) = *(uint4*)o;
  }
}

// ---------------------------------------------------------------------------
// Kernel 1: GI[b][s][j] = sum_h X[b][h][s]*Wih[j][h] + bias[j]  (bf16 out)
// bias[j] = bih[j] + (j<512 ? bhh[j] : 0): the r/z-gate hidden biases are
// additive pre-sigmoid, so they fold into the GEMM epilogue (saves scan regs).
// ---------------------------------------------------------------------------
__global__ __launch_bounds__(512, 4) void gi_gemm(
    const float* __restrict__ X, const unsigned short* __restrict__ Wb,
    const float* __restrict__ bih, const float* __restrict__ bhh,
    unsigned short* __restrict__ gi)
{
  __shared__ __align__(16) char smem[36864];
  unsigned short* Al = (unsigned short*)smem;            // 128 rows x 64 shorts
  unsigned short* Bl = (unsigned short*)(smem + 16384);  // 128 rows x 64 shorts
  float (*Dl)[132] = (float(*)[132])smem;                // epilogue reuse

  const int tid  = threadIdx.x;
  const int lane = tid & 63;
  const int wave = tid >> 6;
  const int wm   = wave >> 2;
  const int wj   = wave & 3;
  const int n16  = lane & 15;
  const int quad = lane >> 4;

  const int mblk = blockIdx.y;
  const int b    = mblk >> 2;
  const int s0   = (mblk & 3) * 128;
  const int j0   = blockIdx.x * 128;

  f32x4 acc[4][2];
#pragma unroll
  for (int mt = 0; mt < 4; mt++)
#pragma unroll
    for (int jt = 0; jt < 2; jt++) acc[mt][jt] = f32x4{0.f, 0.f, 0.f, 0.f};

  const float* Xb = X + (size_t)b * (HH * SSL);

  float4 xa[2][2];   // [pass][h parity]
  uint4  wbv[2];     // B chunks

  auto ldA = [&](int kt, int q, float4* dst) {
    int idx = tid + 512 * q, sq = idx & 31, a = idx >> 5;
    const float* p = Xb + (size_t)(kt * 64 + 2 * a) * SSL + s0 + 4 * sq;
    dst[0] = *(const float4*)p;
    dst[1] = *(const float4*)(p + SSL);
  };
  auto ldB = [&](int kt, int q) -> uint4 {
    int cid = tid + 512 * q, j = cid >> 3, c = cid & 7;
    return *(const uint4*)(Wb + (size_t)(j0 + j) * HH + kt * 64 + c * 8);
  };

  ldA(0, 0, xa[0]); ldA(0, 1, xa[1]);
  wbv[0] = ldB(0, 0); wbv[1] = ldB(0, 1);

  for (int kt = 0; kt < 4; kt++) {
    // stage A: round-to-nearest bf16 pack of an h-pair (even=lo, odd=hi)
#pragma unroll
    for (int q = 0; q < 2; q++) {
      int idx = tid + 512 * q, sq = idx & 31, a = idx >> 5;
      int c = a >> 2, d = a & 3;
#pragma unroll
      for (int r = 0; r < 4; r++) {
        int s = 4 * sq + r;
        int sw = (s + (s >> 3)) & 7;
        unsigned int u =
            (unsigned int)f2bf(((const float*)&xa[q][0])[r]) |
            ((unsigned int)f2bf(((const float*)&xa[q][1])[r]) << 16);
        *(unsigned int*)(Al + s * 64 + ((c ^ sw) * 8) + d * 2) = u;
      }
    }
    // stage B: straight b128 copy into swizzled chunk
#pragma unroll
    for (int p = 0; p < 2; p++) {
      int cid = tid + 512 * p, j = cid >> 3, c = cid & 7;
      int sw = (j + (j >> 3)) & 7;
      *(uint4*)(Bl + j * 64 + ((c ^ sw) * 8)) = wbv[p];
    }
    __syncthreads();
    if (kt < 3) {
      ldA(kt + 1, 0, xa[0]); ldA(kt + 1, 1, xa[1]);
      wbv[0] = ldB(kt + 1, 0); wbv[1] = ldB(kt + 1, 1);
    }
#pragma unroll
    for (int kk = 0; kk < 2; kk++) {
      short8 af[4], bfr[2];
#pragma unroll
      for (int mt = 0; mt < 4; mt++) {
        int s = wm * 64 + mt * 16 + n16;
        int sw = (s + (s >> 3)) & 7;
        af[mt] = *(const short8*)(Al + s * 64 + (((kk * 4 + quad) ^ sw) * 8));
      }
#pragma unroll
      for (int jt = 0; jt < 2; jt++) {
        int j = wj * 32 + jt * 16 + n16;
        int sw = (j + (j >> 3)) & 7;
        bfr[jt] = *(const short8*)(Bl + j * 64 + (((kk * 4 + quad) ^ sw) * 8));
      }
#pragma unroll
      for (int mt = 0; mt < 4; mt++)
#pragma unroll
        for (int jt = 0; jt < 2; jt++)
          acc[mt][jt] = __builtin_amdgcn_mfma_f32_16x16x32_bf16(af[mt], bfr[jt], acc[mt][jt], 0, 0, 0);
    }
    __syncthreads();
  }

  float bias[2];
  {
    int jg0 = j0 + wj * 32 + 0 * 16 + n16;
    int jg1 = j0 + wj * 32 + 1 * 16 + n16;
    bias[0] = bih[jg0] + (jg0 < 2 * HH ? bhh[jg0] : 0.f);
    bias[1] = bih[jg1] + (jg1 < 2 * HH ? bhh[jg1] : 0.f);
  }

  for (int c = 0; c < 2; c++) {
    __syncthreads();
    if (wm == c) {
#pragma unroll
      for (int mt = 0; mt < 4; mt++)
#pragma unroll
        for (int jt = 0; jt < 2; jt++)
#pragma unroll
          for (int r = 0; r < 4; r++)
            Dl[mt * 16 + quad * 4 + r][wj * 32 + jt * 16 + n16] = acc[mt][jt][r] + bias[jt];
    }
    __syncthreads();
#pragma unroll
    for (int i = 0; i < 2; i++) {
      int ml = (tid >> 4) + 32 * i;
      int jj = (tid & 15) * 8;
      float4 p0 = *(const float4*)&Dl[ml][jj];
      float4 p1 = *(const float4*)&Dl[ml][jj + 4];
      short8 st;
      st[0] = (short)f2bf(p0.x); st[1] = (short)f2bf(p0.y);
      st[2] = (short)f2bf(p0.z); st[3] = (short)f2bf(p0.w);
      st[4] = (short)f2bf(p1.x); st[5] = (short)f2bf(p1.y);
      st[6] = (short)f2bf(p1.z); st[7] = (short)f2bf(p1.w);
      int sgl = s0 + c * 64 + ml;
      *(short8*)(gi + ((size_t)b * SSL + sgl) * G3 + j0 + jj) = st;
    }
  }
}

// ---------------------------------------------------------------------------
// Kernel 2: persistent GRU scan. 64 blocks x 4 rows, 512 thr (8 waves).
// KEY (R5 post-mortem): the VGPR allocator pins itself at a 124-reg budget
// and rematerializes W loads from L2 every step (~344 KB/block/step = the
// whole 2900-cy gap). Fix: park W fragments in the AGPR file via "+a" asm
// pins — opaque to remat, separate allocation class, and gfx950 MFMA reads
// A-operands directly from AGPRs. Budget/wave (hard cap arch+acc <= 256 for
// 2 waves/SIMD): 40 frags AGPR (160) + 8 frags (g=2, kt>=4) LDS; acc cut to
// 12 VGPRs via mt-split passes; b_hr/b_hz folded into the GEMM bias.
// ---------------------------------------------------------------------------
__global__ __launch_bounds__(512, 2) void gru_scan(
    const float* __restrict__ tree, const int* __restrict__ mask,
    const unsigned short* __restrict__ wfrag, const float* __restrict__ bhh,
    const unsigned short* __restrict__ gi, float* __restrict__ out)
{
  __shared__ __align__(16) unsigned char lds[82432];  // >80KB => 1 block/CU
  unsigned short* wlds = (unsigned short*)lds;        // 64 frags x 1KB = 65536 B
  unsigned short (*hfrag)[8][4][4][8] =
      (unsigned short(*)[8][4][4][8])(lds + 65536);   // 2 x 2048 B
  float* preF = (float*)(lds + 69632);                // [g][n16][264] = 12672 B
  int*   lsum = (int*)(lds + 82304);                  // 16 B, dedicated

  const int tid  = threadIdx.x;
  const int lane = tid & 63;
  const int w    = tid >> 6;
  const int n16  = lane & 15;
  const int quad = lane >> 4;
  const int brow0 = blockIdx.x * 4;
  const int bb = tid >> 7;           // 0..3
  const int jj = (tid & 127) * 2;    // even j

  if (tid < 4) lsum[tid] = 0;
  // stage 8 LDS frags per wave: g=2, mt 0..1, kt 4..7
#pragma unroll
  for (int i = 0; i < 8; i++) {
    int cid = tid + 512 * i;         // 0..4095
    int l = cid & 63, rest = cid >> 6;       // rest 0..63
    int ktp = rest & 3, mtp = (rest >> 2) & 1, wp = rest >> 3;
    int F = ((wp * 3 + 2) * 2 + mtp) * 8 + (4 + ktp);
    uint4 v = *(const uint4*)(wfrag + ((size_t)F * 64 + l) * 8);
    *(uint4*)(wlds + (((size_t)((wp * 2 + mtp) * 4 + ktp)) * 64 + l) * 8) = v;
  }
  __syncthreads();
  {
    const int* mp = mask + (size_t)(brow0 + bb) * SSL + (tid & 127) * 4;
    atomicAdd(&lsum[bb], mp[0] + mp[1] + mp[2] + mp[3]);
  }

  // AGPR-resident frags: g 0..1 all kt (32) + g=2 kt 0..3 (8) = 40 = 160 AGPR
  short8 aw[2][2][8];
#pragma unroll
  for (int g = 0; g < 2; g++)
#pragma unroll
    for (int mt = 0; mt < 2; mt++)
#pragma unroll
      for (int kt = 0; kt < 8; kt++) {
        int F = ((w * 3 + g) * 2 + mt) * 8 + kt;
        aw[g][mt][kt] = *(const short8*)(wfrag + ((size_t)F * 64 + lane) * 8);
      }
  short8 awC[2][4];
#pragma unroll
  for (int mt = 0; mt < 2; mt++)
#pragma unroll
    for (int kt = 0; kt < 4; kt++) {
      int F = ((w * 3 + 2) * 2 + mt) * 8 + kt;
      awC[mt][kt] = *(const short8*)(wfrag + ((size_t)F * 64 + lane) * 8);
    }
  // Pin into AGPRs: opaque asm — cannot be rematerialized, must stay "a"-class.
#pragma unroll
  for (int g = 0; g < 2; g++)
#pragma unroll
    for (int mt = 0; mt < 2; mt++)
#pragma unroll
      for (int kt = 0; kt < 8; kt++)
        asm volatile("" : "+a"(aw[g][mt][kt]));
#pragma unroll
  for (int mt = 0; mt < 2; mt++)
#pragma unroll
    for (int kt = 0; kt < 4; kt++)
      asm volatile("" : "+a"(awC[mt][kt]));

  float bhn0 = bhh[2 * HH + jj], bhn1 = bhh[2 * HH + jj + 1];

  float h0 = tree[(size_t)(brow0 + bb) * HH + jj];
  float h1 = tree[(size_t)(brow0 + bb) * HH + jj + 1];
  *(unsigned int*)&hfrag[0][jj >> 5][bb][(jj >> 3) & 3][jj & 7] =
      (unsigned int)f2bf(h0) | ((unsigned int)f2bf(h1) << 16);
  __syncthreads();
  int last = lsum[bb] - 1; if (last < 0) last = 0;

  const unsigned short* gib = gi + (size_t)(brow0 + bb) * SSL * G3;
  unsigned int giA[3], giB[3];
#pragma unroll
  for (int g = 0; g < 3; g++) giA[g] = *(const unsigned int*)(gib + (size_t)0 * G3 + g * HH + jj);
#pragma unroll
  for (int g = 0; g < 3; g++) giB[g] = *(const unsigned int*)(gib + (size_t)1 * G3 + g * HH + jj);

  auto step = [&](int t, unsigned int* gv) {
    const int cb = t & 1, nb = cb ^ 1;
    float gir0 = bf2f((unsigned short)(gv[0] & 0xFFFF)), gir1 = bf2f((unsigned short)(gv[0] >> 16));
    float giz0 = bf2f((unsigned short)(gv[1] & 0xFFFF)), giz1 = bf2f((unsigned short)(gv[1] >> 16));
    float gin0 = bf2f((unsigned short)(gv[2] & 0xFFFF)), gin1 = bf2f((unsigned short)(gv[2] >> 16));

    // ---- phase A: gh = Whh . h, mt-split (12 acc VGPRs live at a time) ----
#pragma unroll
    for (int mt = 0; mt < 2; mt++) {
      f32x4 a0 = f32x4{0.f, 0.f, 0.f, 0.f};
      f32x4 a1 = f32x4{0.f, 0.f, 0.f, 0.f};
      f32x4 a2 = f32x4{0.f, 0.f, 0.f, 0.f};
#pragma unroll
      for (int kt = 0; kt < 8; kt++) {
        short8 hb = *(const short8*)&hfrag[cb][kt][n16 & 3][quad][0];
        a0 = __builtin_amdgcn_mfma_f32_16x16x32_bf16(aw[0][mt][kt], hb, a0, 0, 0, 0);
        a1 = __builtin_amdgcn_mfma_f32_16x16x32_bf16(aw[1][mt][kt], hb, a1, 0, 0, 0);
        short8 w2 = (kt < 4) ? awC[mt][kt]
                  : *(const short8*)(wlds + (((size_t)((w * 2 + mt) * 4 + (kt - 4))) * 64 + lane) * 8);
        a2 = __builtin_amdgcn_mfma_f32_16x16x32_bf16(w2, hb, a2, 0, 0, 0);
      }
      if (n16 < 4) {
        *(f32x4*)(preF + 0 * 1056 + n16 * 264 + w * 32 + mt * 16 + quad * 4) = a0;
        *(f32x4*)(preF + 1 * 1056 + n16 * 264 + w * 32 + mt * 16 + quad * 4) = a1;
        *(f32x4*)(preF + 2 * 1056 + n16 * 264 + w * 32 + mt * 16 + quad * 4) = a2;
      }
    }
    int tn = (t + 2 < SSL) ? t + 2 : SSL - 1;
    gv[0] = *(const unsigned int*)(gib + (size_t)tn * G3 + 0 * HH + jj);
    gv[1] = *(const unsigned int*)(gib + (size_t)tn * G3 + 1 * HH + jj);
    gv[2] = *(const unsigned int*)(gib + (size_t)tn * G3 + 2 * HH + jj);
    block_sync_lds();

    // ---- phase B: gates + state update (r/z biases pre-folded into gi) ----
    float2 pr = *(const float2*)(preF + 0 * 1056 + bb * 264 + jj);
    float2 pz = *(const float2*)(preF + 1 * 1056 + bb * 264 + jj);
    float2 pn = *(const float2*)(preF + 2 * 1056 + bb * 264 + jj);
    float hr0 = pr.x + gir0, hr1 = pr.y + gir1;
    float hz0 = pz.x + giz0, hz1 = pz.y + giz1;
    float hn0 = pn.x + bhn0, hn1 = pn.y + bhn1;
    float r0 = __builtin_amdgcn_rcpf(1.f + __expf(-hr0));
    float r1 = __builtin_amdgcn_rcpf(1.f + __expf(-hr1));
    float z0 = __builtin_amdgcn_rcpf(1.f + __expf(-hz0));
    float z1 = __builtin_amdgcn_rcpf(1.f + __expf(-hz1));
    float a0 = gin0 + r0 * hn0, a1 = gin1 + r1 * hn1;
    float nn0 = 1.f - 2.f * __builtin_amdgcn_rcpf(__expf(2.f * a0) + 1.f);
    float nn1 = 1.f - 2.f * __builtin_amdgcn_rcpf(__expf(2.f * a1) + 1.f);
    float hN0 = nn0 + z0 * (h0 - nn0);
    float hN1 = nn1 + z1 * (h1 - nn1);
    h0 = hN0; h1 = hN1;
    *(unsigned int*)&hfrag[nb][jj >> 5][bb][(jj >> 3) & 3][jj & 7] =
        (unsigned int)f2bf(hN0) | ((unsigned int)f2bf(hN1) << 16);
    if (t == last) {
      out[(size_t)(brow0 + bb) * HH + jj] = hN0;
      out[(size_t)(brow0 + bb) * HH + jj + 1] = hN1;
    }
    block_sync_lds();
  };

  for (int t = 0; t < SSL; t += 2) {
    step(t, giA);
    step(t + 1, giB);
  }
}

extern "C" void kernel_launch(void* const* d_in, const int* in_sizes, int n_in,
                              void* d_out, int out_size, void* d_ws, size_t ws_size,
                              hipStream_t stream) {
  const float* tree = (const float*)d_in[0];
  const float* seq  = (const float*)d_in[1];
  const int*   mask = (const int*)d_in[2];
  const float* Wih  = (const float*)d_in[3];
  const float* Whh  = (const float*)d_in[4];
  const float* bih  = (const float*)d_in[5];
  const float* bhh  = (const float*)d_in[6];
  float* out = (float*)d_out;

  unsigned short* gi      = (unsigned short*)d_ws;                       // 201,326,592 B
  unsigned short* wih_bf  = (unsigned short*)((char*)d_ws + 201326592);  // 393,216 B
  unsigned short* whh_frag= (unsigned short*)((char*)d_ws + 201719808);  // 393,216 B

  prep_pack<<<192, 256, 0, stream>>>(Wih, Whh, wih_bf, whh_frag);
  gi_gemm<<<dim3(6, 1024), 512, 0, stream>>>(seq, wih_bf, bih, bhh, gi);
  gru_scan<<<64, 512, 0, stream>>>(tree, mask, whh_frag, bhh, gi, out);
}